// Round 10
// baseline (63.403 us; speedup 1.0000x reference)
//
#include <hip/hip_runtime.h>
#include <math.h>

#define H 1024
#define V 50257
#define S 2048
#define NCH 128            // attention chunks (16 s-rows each)
#define NGPRE 512          // gpre blocks (8 gate-rows each)
#define NLOG 6283          // logits blocks (8 rows each)

// ws float offsets (16-float aligned)
#define O_CTXP   0                    // NCH*H = 131072
#define O_Z      131072               // H
#define O_GPRE   132096               // 4H  (W_hh@h0 + b_ih + b_hh)
#define O_HNEW   136192               // H
#define O_PART   137216               // 2*NLOG

typedef float vf4 __attribute__((ext_vector_type(4)));   // native vec for nontemporal

__device__ inline float wred_sum(float v) {
    for (int o = 32; o > 0; o >>= 1) v += __shfl_down(v, o, 64);
    return v;
}
__device__ inline float sigm(float x) { return 1.f / (1.f + expf(-x)); }
__device__ inline float dot4(float4 a, float4 b) {
    return a.x*b.x + a.y*b.y + a.z*b.z + a.w*b.w;
}
__device__ inline float dot4v(vf4 w, float4 b) {
    return w.x*b.x + w.y*b.y + w.z*b.z + w.w*b.w;
}

// ---- K1 (NCH+NGPRE blocks): b<NCH: attn chunk (coeff + ctxp partial, 16 rows);
//      b>=NCH: gpre rows = W_hh@h0 + b_ih + b_hh (8 rows/block) ----
__global__ __launch_bounds__(256) void k_attn(const float* __restrict__ enc,
        const float* __restrict__ h0, const float* __restrict__ attn_W,
        const float* __restrict__ attn_b, const float* __restrict__ W_hh,
        const float* __restrict__ b_ih, const float* __restrict__ b_hh,
        float* __restrict__ ws) {
    const int b = blockIdx.x, t = threadIdx.x, lane = t & 63, wave = t >> 6;
    if (b < NCH) {
        __shared__ float sred[4];
        __shared__ float scoef[16];
        // hdot = dot(h0, attn_W[H:2H]) + attn_b  (block-redundant, 8KB)
        float4 hv4 = ((const float4*)h0)[t];
        float4 wv4 = ((const float4*)(attn_W + H))[t];
        float p = wred_sum(dot4(hv4, wv4));
        if (lane == 0) sred[wave] = p;
        __syncthreads();
        const float hdot = sred[0] + sred[1] + sred[2] + sred[3] + attn_b[0];
        // coeff: wave owns 4 rows (ILP 4)
        const float4* w0 = (const float4*)attn_W;
        const int s0 = b * 16;
        {
            int sb = s0 + wave * 4;
            const float4* e0 = (const float4*)(enc + (size_t)(sb    ) * H);
            const float4* e1 = (const float4*)(enc + (size_t)(sb + 1) * H);
            const float4* e2 = (const float4*)(enc + (size_t)(sb + 2) * H);
            const float4* e3 = (const float4*)(enc + (size_t)(sb + 3) * H);
            float a0 = 0.f, a1 = 0.f, a2 = 0.f, a3 = 0.f;
            #pragma unroll
            for (int kk = 0; kk < 4; ++kk) {
                int k4 = kk * 64 + lane;
                float4 w = w0[k4];
                a0 += dot4(e0[k4], w); a1 += dot4(e1[k4], w);
                a2 += dot4(e2[k4], w); a3 += dot4(e3[k4], w);
            }
            a0 = wred_sum(a0); a1 = wred_sum(a1);
            a2 = wred_sum(a2); a3 = wred_sum(a3);
            if (lane == 0) {
                scoef[wave*4 + 0] = a0 + hdot;
                scoef[wave*4 + 1] = a1 + hdot;
                scoef[wave*4 + 2] = a2 + hdot;
                scoef[wave*4 + 3] = a3 + hdot;
            }
        }
        __syncthreads();
        // ctxp[b][j]: 2nd pass over the 16 rows (L2-hot)
        float4 a4 = make_float4(0.f, 0.f, 0.f, 0.f);
        #pragma unroll 4
        for (int rr = 0; rr < 16; ++rr) {
            float c = scoef[rr];
            float4 e = ((const float4*)(enc + (size_t)(s0 + rr) * H))[t];
            a4.x += c * e.x; a4.y += c * e.y; a4.z += c * e.z; a4.w += c * e.w;
        }
        ((float4*)(ws + O_CTXP + b * H))[t] = a4;
    } else {
        // gpre: 8 gate-rows per block; wave owns 2 rows (ILP 2)
        const int bb = b - NCH;            // 0..NGPRE-1
        float4 hr[4];
        #pragma unroll
        for (int kk = 0; kk < 4; ++kk) hr[kk] = ((const float4*)h0)[kk*64 + lane];
        const int r0 = bb * 8 + wave * 2;
        const float4* m0 = (const float4*)(W_hh + (size_t)(r0    ) * H);
        const float4* m1 = (const float4*)(W_hh + (size_t)(r0 + 1) * H);
        float a0 = 0.f, a1 = 0.f;
        #pragma unroll
        for (int kk = 0; kk < 4; ++kk) {
            int k4 = kk * 64 + lane;
            float4 a = hr[kk];
            a0 += dot4(m0[k4], a); a1 += dot4(m1[k4], a);
        }
        a0 = wred_sum(a0); a1 = wred_sum(a1);
        if (lane == 0) {
            ws[O_GPRE + r0    ] = a0 + b_ih[r0    ] + b_hh[r0    ];
            ws[O_GPRE + r0 + 1] = a1 + b_ih[r0 + 1] + b_hh[r0 + 1];
        }
    }
}

// ---- K2 (64 blocks x 512): ctx reduce (split across thread-halves) + 16 z rows ----
__global__ __launch_bounds__(512) void k_z(const float* __restrict__ emb,
        const int* __restrict__ ids, const float* __restrict__ comb_W,
        const float* __restrict__ comb_b, float* __restrict__ ws) {
    const int b = blockIdx.x, t = threadIdx.x, lane = t & 63, wave = t >> 6;
    __shared__ __align__(16) float spart[2][H];
    __shared__ __align__(16) float sctx[H];
    // reduce: half 0 sums chunks 0..63, half 1 sums 64..127, over float4 slot fi
    {
        const int half = t >> 8, fi = t & 255;
        float4 a4 = make_float4(0.f, 0.f, 0.f, 0.f);
        #pragma unroll 8
        for (int ch = half * 64; ch < half * 64 + 64; ++ch) {
            float4 v = ((const float4*)(ws + O_CTXP + ch * H))[fi];
            a4.x += v.x; a4.y += v.y; a4.z += v.z; a4.w += v.w;
        }
        ((float4*)spart[half])[fi] = a4;
    }
    __syncthreads();
    if (t < 256) {
        float4 p0 = ((const float4*)spart[0])[t];
        float4 p1 = ((const float4*)spart[1])[t];
        p0.x += p1.x; p0.y += p1.y; p0.z += p1.z; p0.w += p1.w;
        ((float4*)sctx)[t] = p0;
    }
    __syncthreads();

    const int tok = ids[0];
    const float4* x4 = (const float4*)(emb + (size_t)tok * H);
    const float4* c4 = (const float4*)sctx;
    // 8 waves x 2 rows (ILP 2): i = b*16 + wave*2 + {0,1}
    const int i0 = b * 16 + wave * 2;
    const float4* wr0 = (const float4*)(comb_W + (size_t)i0 * 2 * H);
    const float4* wr1 = (const float4*)(comb_W + (size_t)(i0 + 1) * 2 * H);
    float a0 = 0.f, a1 = 0.f;
    #pragma unroll
    for (int kk = 0; kk < 4; ++kk) {
        int k4 = kk * 64 + lane;
        float4 xv = x4[k4], cv = c4[k4];
        a0 += dot4(wr0[k4], xv) + dot4(wr0[256 + k4], cv);
        a1 += dot4(wr1[k4], xv) + dot4(wr1[256 + k4], cv);
    }
    a0 = wred_sum(a0); a1 = wred_sum(a1);
    if (lane == 0) {
        ws[O_Z + i0    ] = fmaxf(a0 + comb_b[i0    ], 0.f);
        ws[O_Z + i0 + 1] = fmaxf(a1 + comb_b[i0 + 1], 0.f);
    }
}

// ---- K3 (1024 blocks): gates = W_ih@z + gpre; LSTM pointwise; block = j ----
__global__ __launch_bounds__(256) void k_gates_lstm(const float* __restrict__ W_ih,
        const float* __restrict__ c0, float* __restrict__ ws, float* __restrict__ out) {
    const int j = blockIdx.x, t = threadIdx.x, lane = t & 63, g = t >> 6;
    __shared__ float sg[4];
    const int row = g * H + j;
    const float4* wi = (const float4*)(W_ih + (size_t)row * H);
    const float4* zv = (const float4*)(ws + O_Z);
    float acc = 0.f;
    #pragma unroll
    for (int kk = 0; kk < 4; ++kk) {
        int k4 = kk * 64 + lane;
        acc += dot4(wi[k4], zv[k4]);
    }
    acc = wred_sum(acc);
    if (lane == 0) sg[g] = acc + ws[O_GPRE + row];
    __syncthreads();
    if (t == 0) {
        float ig = sigm(sg[0]);
        float fg = sigm(sg[1]);
        float gg = tanhf(sg[2]);
        float og = sigm(sg[3]);
        float cn = fg * c0[j] + ig * gg;
        float hn = og * tanhf(cn);
        out[V + j]     = hn;
        out[V + H + j] = cn;
        ws[O_HNEW + j] = hn;
    }
}

// ---- K4 (NLOG blocks x 512): logits GEMV, wave per row; raw logits -> out;
//      out_W via nontemporal loads (zero reuse; keep L2 for hot ws lines) ----
__global__ __launch_bounds__(512) void k_logits(const float* __restrict__ out_W,
        const float* __restrict__ out_b, float* __restrict__ ws,
        float* __restrict__ out) {
    const int t = threadIdx.x, lane = t & 63, wave = t >> 6;   // 8 waves
    __shared__ float slg[8];
    const float4* hv = (const float4*)(ws + O_HNEW);
    float4 hr[4];
    #pragma unroll
    for (int kk = 0; kk < 4; ++kk) hr[kk] = hv[kk * 64 + lane];
    const int v = blockIdx.x * 8 + wave;
    const bool q = v < V;
    const vf4* wr = (const vf4*)(out_W + (size_t)(q ? v : 0) * H);
    float acc = 0.f;
    #pragma unroll
    for (int kk = 0; kk < 4; ++kk) {
        int k4 = kk * 64 + lane;
        vf4 w = __builtin_nontemporal_load(&wr[k4]);
        acc += dot4v(w, hr[kk]);
    }
    acc = wred_sum(acc);
    if (lane == 0) {
        float lg = acc + out_b[q ? v : 0];
        if (q) out[v] = lg;
        slg[wave] = q ? lg : -1e30f;
    }
    __syncthreads();
    if (t == 0) {
        float m = slg[0];
        #pragma unroll
        for (int i = 1; i < 8; ++i) m = fmaxf(m, slg[i]);
        float s = 0.f;
        #pragma unroll
        for (int i = 0; i < 8; ++i) s += expf(slg[i] - m);
        ws[O_PART + 2 * blockIdx.x]     = m;
        ws[O_PART + 2 * blockIdx.x + 1] = s;
    }
}

// ---- K5 (50 blocks x 1024): combine partials -> lse (redundant); out -= lse ----
__global__ __launch_bounds__(1024) void k_logp(const float* __restrict__ ws,
        float* __restrict__ out) {
    const int t = threadIdx.x, lane = t & 63, wv = t >> 6;
    __shared__ float smm[16], sss[16];
    __shared__ float slse;
    float m = -1e30f, s = 0.f;
    for (int i = t; i < NLOG; i += 1024) {
        float m2 = ws[O_PART + 2 * i], s2 = ws[O_PART + 2 * i + 1];
        float M = fmaxf(m, m2);
        s = s * expf(m - M) + s2 * expf(m2 - M);
        m = M;
    }
    for (int o = 32; o > 0; o >>= 1) {
        float m2 = __shfl_down(m, o, 64), s2 = __shfl_down(s, o, 64);
        float M = fmaxf(m, m2);
        s = s * expf(m - M) + s2 * expf(m2 - M);
        m = M;
    }
    if (lane == 0) { smm[wv] = m; sss[wv] = s; }
    __syncthreads();
    if (t == 0) {
        float M = smm[0], Ssum = sss[0];
        #pragma unroll
        for (int i = 1; i < 16; ++i) {
            float MM = fmaxf(M, smm[i]);
            Ssum = Ssum * expf(M - MM) + sss[i] * expf(smm[i] - MM);
            M = MM;
        }
        slse = M + logf(Ssum);
    }
    __syncthreads();
    const float lse = slse;
    const int v = blockIdx.x * 1024 + t;
    if (v < V) out[v] = out[v] - lse;
}

extern "C" void kernel_launch(void* const* d_in, const int* in_sizes, int n_in,
                              void* d_out, int out_size, void* d_ws, size_t ws_size,
                              hipStream_t stream) {
    const int*   ids    = (const int*)  d_in[0];
    const float* h0     = (const float*)d_in[1];
    const float* c0     = (const float*)d_in[2];
    const float* enc    = (const float*)d_in[3];
    const float* emb    = (const float*)d_in[4];
    const float* attn_W = (const float*)d_in[5];
    const float* attn_b = (const float*)d_in[6];
    const float* comb_W = (const float*)d_in[7];
    const float* comb_b = (const float*)d_in[8];
    const float* W_ih   = (const float*)d_in[9];
    const float* W_hh   = (const float*)d_in[10];
    const float* b_ih   = (const float*)d_in[11];
    const float* b_hh   = (const float*)d_in[12];
    const float* out_W  = (const float*)d_in[13];
    const float* out_b  = (const float*)d_in[14];
    float* out = (float*)d_out;
    float* ws  = (float*)d_ws;

    k_attn      <<<NCH + NGPRE, 256, 0, stream>>>(enc, h0, attn_W, attn_b,
                                                  W_hh, b_ih, b_hh, ws);
    k_z         <<<64, 512, 0, stream>>>(emb, ids, comb_W, comb_b, ws);
    k_gates_lstm<<<1024, 256, 0, stream>>>(W_ih, c0, ws, out);
    k_logits    <<<NLOG, 512, 0, stream>>>(out_W, out_b, ws, out);
    k_logp      <<<50, 1024, 0, stream>>>(ws, out);
}